// Round 1
// baseline (1281.121 us; speedup 1.0000x reference)
//
#include <hip/hip_runtime.h>
#include <hip/hip_bf16.h>
#include <math.h>

// Transformer block for MI355X (gfx950). Inputs/outputs are FLOAT32 (per the
// reference contract); compute is bf16-MFMA internally.
// GEMMs: m97 structure (128x128 tile, BK=32, global_load_lds width 16).
// Attention: per-wave flash (16 q-rows/wave), MFMA QK^T and PV.
//   R4: V is pre-transposed to vT[b][h][d][s] (kernel vt_k) so the PV B-frag
//   is one contiguous bf16x8 load instead of 8 scalar 4KB-strided loads;
//   q-tile dispatch reversed (heavy causal blocks first) to kill the tail.
// Weights converted f32->bf16 just-in-time into one rotating workspace slot.
// vT overlays the weight slot (dead between Wv GEMM and Wo cvt).

typedef __bf16 bf16x8 __attribute__((ext_vector_type(8)));
typedef float f32x4 __attribute__((ext_vector_type(4)));

#define MFMA16(a, b, c) __builtin_amdgcn_mfma_f32_16x16x32_bf16(a, b, c, 0, 0, 0)

__device__ __forceinline__ void async_cp16(const void* g, void* l) {
  __builtin_amdgcn_global_load_lds((__attribute__((address_space(1))) void*)g,
                                   (__attribute__((address_space(3))) void*)l,
                                   16, 0, 0);
}

// --------------------------------------------------------------- f32 -> bf16
__global__ __launch_bounds__(256) void cvt_k(const float* __restrict__ s,
                                             __bf16* __restrict__ d, long n) {
  const long i = ((long)blockIdx.x * 256 + threadIdx.x) * 8;
  if (i >= n) return;
  f32x4 a = *(const f32x4*)(s + i);
  f32x4 b = *(const f32x4*)(s + i + 4);
  bf16x8 o;
#pragma unroll
  for (int j = 0; j < 4; ++j) {
    o[j] = (__bf16)a[j];
    o[4 + j] = (__bf16)b[j];
  }
  *(bf16x8*)(d + i) = o;
}

// ---------------------------------------------------------------- GEMM (B^T)
// C[M,N] = A[M,K] * B[N,K]^T   (A,B bf16; C dtype CT)
// EPI=0: store. EPI=1: += R (residual). EPI=2: *= silu(R) (R=w1x, in-place h).
template <int EPI, typename CT, typename RT>
__global__ __launch_bounds__(256) void gemm_bt(
    const __bf16* __restrict__ A, const __bf16* __restrict__ B,
    CT* C, const RT* R, int M, int N, int K) {
  __shared__ __attribute__((aligned(16))) __bf16 sA[128 * 32];
  __shared__ __attribute__((aligned(16))) __bf16 sB[128 * 32];
  const int tid = threadIdx.x;
  const int lane = tid & 63;
  const int wave = tid >> 6;
  const int wm = (wave >> 1) << 6;   // wave's 64x64 quadrant
  const int wn = (wave & 1) << 6;
  const int ln15 = lane & 15;
  const int kq8 = (lane >> 4) << 3;  // quad*8
  const long blockM = (long)blockIdx.y << 7;
  const long blockN = (long)blockIdx.x << 7;

  // staging: thread t covers row t/4 (and +64), k-cols (t%4)*8..+8; LDS dest is
  // linear in lane (base + lane*16B) per the global_load_lds G5 caveat.
  const int srow = tid >> 2;
  const int scol = (tid & 3) << 3;
  const __bf16* gA = A + (blockM + srow) * (long)K + scol;
  const __bf16* gB = B + (blockN + srow) * (long)K + scol;
  __bf16* lA = sA + tid * 8;
  __bf16* lB = sB + tid * 8;

  f32x4 acc[4][4] = {};
  const int KT = K >> 5;

  async_cp16(gA, lA);
  async_cp16(gA + 64 * (long)K, lA + 2048);
  async_cp16(gB, lB);
  async_cp16(gB + 64 * (long)K, lB + 2048);

  for (int kt = 0; kt < KT; ++kt) {
    __builtin_amdgcn_s_waitcnt(0);  // drain this wave's global_load_lds
    __syncthreads();                // all waves' staging visible
    bf16x8 af[4], bfr[4];
#pragma unroll
    for (int i = 0; i < 4; ++i)
      af[i] = *(const bf16x8*)&sA[(wm + i * 16 + ln15) * 32 + kq8];
#pragma unroll
    for (int j = 0; j < 4; ++j)
      bfr[j] = *(const bf16x8*)&sB[(wn + j * 16 + ln15) * 32 + kq8];
    __syncthreads();                // frag reads done before re-staging
    if (kt + 1 < KT) {
      const __bf16* a2 = gA + (long)(kt + 1) * 32;
      const __bf16* b2 = gB + (long)(kt + 1) * 32;
      async_cp16(a2, lA);
      async_cp16(a2 + 64 * (long)K, lA + 2048);
      async_cp16(b2, lB);
      async_cp16(b2 + 64 * (long)K, lB + 2048);
    }
#pragma unroll
    for (int i = 0; i < 4; ++i)
#pragma unroll
      for (int j = 0; j < 4; ++j)
        acc[i][j] = MFMA16(af[i], bfr[j], acc[i][j]);
  }

  // C/D layout (m89): col = lane&15, row = quad*4 + reg
  const int rq4 = (lane >> 4) << 2;
#pragma unroll
  for (int i = 0; i < 4; ++i)
#pragma unroll
    for (int j = 0; j < 4; ++j)
#pragma unroll
      for (int r = 0; r < 4; ++r) {
        const long grow = blockM + wm + i * 16 + rq4 + r;
        const long gcol = blockN + wn + j * 16 + ln15;
        const long idx = grow * N + gcol;
        float v = acc[i][j][r];
        if (EPI == 1) v += (float)R[idx];
        if (EPI == 2) {
          const float w = (float)R[idx];
          v *= w / (1.f + __expf(-w));  // silu(w1x) * (xn2.W3^T)
        }
        C[idx] = (CT)v;
      }
}

// -------------------------------------------------- V transpose: [b,s,c] -> [b,c,s]
// c = h*128+d (2048 cols). Output vt[(b*2048 + c)*2048 + s]. Tiles: 32 s x 64 c.
__global__ __launch_bounds__(256) void vt_k(const __bf16* __restrict__ v,
                                            __bf16* __restrict__ vt) {
  __shared__ __bf16 sT[64 * 40];  // [c][s], stride 40 keeps 16B alignment
  const int t = threadIdx.x;
  const int s0 = blockIdx.x << 5;
  const int c0 = blockIdx.y << 6;
  const long b = blockIdx.z;
  const int sl = t >> 3;          // 0..31
  const int cg = (t & 7) << 3;    // 0..56
  bf16x8 val = *(const bf16x8*)(v + (b * 2048 + s0 + sl) * 2048L + c0 + cg);
#pragma unroll
  for (int j = 0; j < 8; ++j) sT[(cg + j) * 40 + sl] = val[j];
  __syncthreads();
  const int cl = t >> 2;          // 0..63
  const int sg = (t & 3) << 3;    // 0..24
  bf16x8 o = *(const bf16x8*)&sT[cl * 40 + sg];
  *(bf16x8*)(vt + (b * 2048 + c0 + cl) * 2048L + s0 + sg) = o;
}

// ------------------------------------------------------------ flash attention
// one wave per (b, h, 16 q-rows); key tiles of 32; causal; finite sentinels.
// V consumed pre-transposed (vt[b][h][d][s]) -> PV B-frag is one bf16x8 load.
__global__ __launch_bounds__(64) void attn_k(
    const __bf16* __restrict__ q, const __bf16* __restrict__ k,
    const __bf16* __restrict__ vt, __bf16* __restrict__ o) {
  __shared__ __attribute__((aligned(16))) __bf16 sP[16 * 32];
  const int lane = threadIdx.x;
  const int ln15 = lane & 15;
  const int quad = lane >> 4;
  const int qt = (int)gridDim.x - 1 - (int)blockIdx.x;  // heavy blocks first
  const int h = blockIdx.y;
  const int b = blockIdx.z;
  const int S = 2048;
  const int qb = qt << 4;
  const long bh = (long)b * S * 2048 + h * 128;
  const __bf16* vtp = vt + ((long)b * 2048 + h * 128) * 2048;  // [128][2048]
  const float NEG = -1.0e4f;  // finite; |true score| < ~1e2

  bf16x8 qf[4];  // A-frag (m120): Q[m=ln15][d = kb*32 + quad*8 + j]
  const __bf16* qp = q + bh + (long)(qb + ln15) * 2048 + quad * 8;
#pragma unroll
  for (int kb = 0; kb < 4; ++kb) qf[kb] = *(const bf16x8*)(qp + kb * 32);

  f32x4 oacc[8] = {};
  float mrow[4] = {NEG, NEG, NEG, NEG};
  float lrow[4] = {};
  const float scale = 0.08838834764831845f;  // 1/sqrt(128)

  const int nkt = (qt + 2) >> 1;
  for (int kt = 0; kt < nkt; ++kt) {
    const int kbase = kt << 5;
    f32x4 s[2] = {};
#pragma unroll
    for (int c = 0; c < 2; ++c) {
      const __bf16* kp = k + bh + (long)(kbase + c * 16 + ln15) * 2048 + quad * 8;
#pragma unroll
      for (int kb = 0; kb < 4; ++kb) {
        bf16x8 kf = *(const bf16x8*)(kp + kb * 32);
        s[c] = MFMA16(qf[kb], kf, s[c]);
      }
    }
#pragma unroll
    for (int r = 0; r < 4; ++r) {
      const int qrow = qb + quad * 4 + r;
      const bool m0 = (kbase + ln15 > qrow);
      const bool m1 = (kbase + 16 + ln15 > qrow);
      const float s0 = m0 ? NEG : s[0][r] * scale;
      const float s1 = m1 ? NEG : s[1][r] * scale;
      float tm = fmaxf(s0, s1);
#pragma unroll
      for (int off = 1; off < 16; off <<= 1) tm = fmaxf(tm, __shfl_xor(tm, off));
      const float mnew = fmaxf(mrow[r], tm);
      const float alpha = __expf(mrow[r] - mnew);  // arg <= 0: no inf
      mrow[r] = mnew;
      const float p0 = m0 ? 0.f : __expf(s0 - mnew);
      const float p1 = m1 ? 0.f : __expf(s1 - mnew);
      float rs = p0 + p1;
#pragma unroll
      for (int off = 1; off < 16; off <<= 1) rs += __shfl_xor(rs, off);
      lrow[r] = lrow[r] * alpha + rs;
#pragma unroll
      for (int nt = 0; nt < 8; ++nt) oacc[nt][r] *= alpha;
      sP[(quad * 4 + r) * 32 + ln15] = (__bf16)p0;
      sP[(quad * 4 + r) * 32 + 16 + ln15] = (__bf16)p1;
    }
    __syncthreads();  // P writes -> visible for transposed read
    bf16x8 pa = *(const bf16x8*)&sP[ln15 * 32 + quad * 8];  // A-layout P
    __syncthreads();  // read retired before next iter's writes
#pragma unroll
    for (int nt = 0; nt < 8; ++nt) {
      // B-frag: V[key = kbase + quad*8 + j][dim = nt*16 + ln15], contiguous in vT
      bf16x8 vf = *(const bf16x8*)(vtp + (long)(nt * 16 + ln15) * 2048 +
                                   kbase + quad * 8);
      oacc[nt] = MFMA16(pa, vf, oacc[nt]);
    }
  }

  __bf16* op = o + bh + (long)qb * 2048;
#pragma unroll
  for (int nt = 0; nt < 8; ++nt)
#pragma unroll
    for (int r = 0; r < 4; ++r)
      op[(long)(quad * 4 + r) * 2048 + nt * 16 + ln15] =
          (__bf16)(oacc[nt][r] / lrow[r]);
}

// ------------------------------------------------------ RMSNorm (f32 -> bf16)
__global__ __launch_bounds__(256) void rmsnorm_k(
    const float* __restrict__ x, const float* __restrict__ g,
    __bf16* __restrict__ out) {
  __shared__ float red[4];
  const int row = blockIdx.x;
  const int tid = threadIdx.x;
  f32x4 xa = *(const f32x4*)(x + (long)row * 2048 + tid * 8);
  f32x4 xb = *(const f32x4*)(x + (long)row * 2048 + tid * 8 + 4);
  float xf[8];
  float ss = 0.f;
#pragma unroll
  for (int j = 0; j < 4; ++j) {
    xf[j] = xa[j];
    xf[4 + j] = xb[j];
  }
#pragma unroll
  for (int j = 0; j < 8; ++j) ss += xf[j] * xf[j];
#pragma unroll
  for (int off = 32; off > 0; off >>= 1) ss += __shfl_xor(ss, off);
  if ((tid & 63) == 0) red[tid >> 6] = ss;
  __syncthreads();
  const float inv = rsqrtf((red[0] + red[1] + red[2] + red[3]) * (1.f / 2048.f) + 1e-5f);
  f32x4 ga = *(const f32x4*)(g + tid * 8);
  f32x4 gb = *(const f32x4*)(g + tid * 8 + 4);
  bf16x8 ov;
#pragma unroll
  for (int j = 0; j < 4; ++j) {
    ov[j] = (__bf16)(xf[j] * inv * ga[j]);
    ov[4 + j] = (__bf16)(xf[4 + j] * inv * gb[j]);
  }
  *(bf16x8*)(out + (long)row * 2048 + tid * 8) = ov;
}

// ----------------------------------------------------------------- RoPE (bf16)
__global__ __launch_bounds__(256) void rope_k(__bf16* __restrict__ t) {
  const long idx = (long)blockIdx.x * 256 + threadIdx.x;  // (row, h, kpair)
  const int kp = idx & 63;
  const int h = (idx >> 6) & 15;
  const long row = idx >> 10;
  const int pos = (int)(row & 2047);
  const float freq = exp2f((float)kp * (-13.287712379549449f / 64.0f));
  float sn, cs;
  sincosf((float)pos * freq, &sn, &cs);
  __bf16* p = t + row * 2048 + h * 128 + kp * 2;
  const float e = (float)p[0], od = (float)p[1];
  p[0] = (__bf16)(e * cs - od * sn);
  p[1] = (__bf16)(e * sn + od * cs);
}

// -------------------------------------------------------------------- launcher
extern "C" void kernel_launch(void* const* d_in, const int* in_sizes, int n_in,
                              void* d_out, int out_size, void* d_ws, size_t ws_size,
                              hipStream_t stream) {
  const float* x = (const float*)d_in[0];
  const float* Wq = (const float*)d_in[1];
  const float* Wk = (const float*)d_in[2];
  const float* Wv = (const float*)d_in[3];
  const float* Wo = (const float*)d_in[4];
  const float* W1 = (const float*)d_in[5];
  const float* W2 = (const float*)d_in[6];
  const float* W3 = (const float*)d_in[7];
  const float* g1 = (const float*)d_in[8];
  const float* g2 = (const float*)d_in[9];
  float* out = (float*)d_out;
  char* ws = (char*)d_ws;

  const long NDD = 2048L * 2048;   // 4,194,304
  const long NFD = 5504L * 2048;   // 11,272,192
  const long WSLOT = 22544384;     // NFD * 2 bytes (max weight, bf16)
  const long MB16 = 16777216;      // 4096*2048*2 bytes (bf16 activation)

  __bf16* wslot = (__bf16*)(ws);                  // rotating bf16 weight
  __bf16* xn = (__bf16*)(ws + WSLOT);             // rmsnorm1 out / attn out
  __bf16* qb = (__bf16*)(ws + WSLOT + MB16);      // q
  __bf16* kb = (__bf16*)(ws + WSLOT + 2 * MB16);  // k
  __bf16* vb = (__bf16*)(ws + WSLOT + 3 * MB16);  // v
  __bf16* attn = xn;
  __bf16* vtb = wslot;     // vT (16.8MB) overlays weight slot: dead between
                           // Wv GEMM and Wo cvt (both stream-ordered around attn)
  __bf16* xn2 = vb;        // v dead after vt_k; rmsnorm2 out lives here
  __bf16* w1x = xn;        // 43MB over dead xn+q+k span [WSLOT, WSLOT+45.1MB);
                           // ends 67.6MB < xn2 offset 72.9MB -- disjoint.
  // peak ws: WSLOT + 4*MB16 = 89.7MB

  rmsnorm_k<<<4096, 256, 0, stream>>>(x, g1, xn);

  cvt_k<<<2048, 256, 0, stream>>>(Wq, wslot, NDD);
  gemm_bt<0, __bf16, float><<<dim3(16, 32), 256, 0, stream>>>(
      xn, wslot, qb, nullptr, 4096, 2048, 2048);
  cvt_k<<<2048, 256, 0, stream>>>(Wk, wslot, NDD);
  gemm_bt<0, __bf16, float><<<dim3(16, 32), 256, 0, stream>>>(
      xn, wslot, kb, nullptr, 4096, 2048, 2048);
  cvt_k<<<2048, 256, 0, stream>>>(Wv, wslot, NDD);
  gemm_bt<0, __bf16, float><<<dim3(16, 32), 256, 0, stream>>>(
      xn, wslot, vb, nullptr, 4096, 2048, 2048);

  vt_k<<<dim3(64, 32, 2), 256, 0, stream>>>(vb, vtb);  // vT into dead wslot
  rope_k<<<16384, 256, 0, stream>>>(qb);
  rope_k<<<16384, 256, 0, stream>>>(kb);
  attn_k<<<dim3(128, 16, 2), 64, 0, stream>>>(qb, kb, vtb, attn);

  cvt_k<<<2048, 256, 0, stream>>>(Wo, wslot, NDD);
  gemm_bt<1, float, float><<<dim3(16, 32), 256, 0, stream>>>(
      attn, wslot, out, x, 4096, 2048, 2048);  // out = attn.Wo^T + x (f32)

  rmsnorm_k<<<4096, 256, 0, stream>>>(out, g2, xn2);

  cvt_k<<<5504, 256, 0, stream>>>(W1, wslot, NFD);
  gemm_bt<0, __bf16, float><<<dim3(43, 32), 256, 0, stream>>>(
      xn2, wslot, w1x, nullptr, 4096, 5504, 2048);
  cvt_k<<<5504, 256, 0, stream>>>(W3, wslot, NFD);
  gemm_bt<2, __bf16, __bf16><<<dim3(43, 32), 256, 0, stream>>>(
      xn2, wslot, w1x, w1x, 4096, 5504, 2048);  // h = silu(w1x)*w3x in-place
  cvt_k<<<5504, 256, 0, stream>>>(W2, wslot, NFD);
  gemm_bt<1, float, float><<<dim3(16, 32), 256, 0, stream>>>(
      w1x, wslot, out, out, 4096, 2048, 5504);  // out += h.W2^T (f32)
}

// Round 2
// 1027.721 us; speedup vs baseline: 1.2466x; 1.2466x over previous
//
#include <hip/hip_runtime.h>
#include <hip/hip_bf16.h>
#include <math.h>

// Transformer block for MI355X (gfx950). Inputs/outputs are FLOAT32 (per the
// reference contract); compute is bf16-MFMA internally.
// GEMMs: m97 structure (128x128 tile, BK=32, global_load_lds width 16).
// Attention: per-wave flash (MFMA QK^T and PV, LDS P-transpose).
//   R5: reverted R4's vT experiment (scatter reads regressed). Each wave now
//   owns a BALANCED PAIR of q-tiles (p, 127-p): constant work per wave (no
//   causal tail), K/V fragment loads shared between the two tiles, 2x ILP.
//   Blocks are XCD-clustered so each XCD's L2 holds 4 (b,h) K/V panels (4MB).
// Weights converted f32->bf16 just-in-time into one rotating workspace slot.

typedef __bf16 bf16x8 __attribute__((ext_vector_type(8)));
typedef float f32x4 __attribute__((ext_vector_type(4)));

#define MFMA16(a, b, c) __builtin_amdgcn_mfma_f32_16x16x32_bf16(a, b, c, 0, 0, 0)

__device__ __forceinline__ void async_cp16(const void* g, void* l) {
  __builtin_amdgcn_global_load_lds((__attribute__((address_space(1))) void*)g,
                                   (__attribute__((address_space(3))) void*)l,
                                   16, 0, 0);
}

// --------------------------------------------------------------- f32 -> bf16
__global__ __launch_bounds__(256) void cvt_k(const float* __restrict__ s,
                                             __bf16* __restrict__ d, long n) {
  const long i = ((long)blockIdx.x * 256 + threadIdx.x) * 8;
  if (i >= n) return;
  f32x4 a = *(const f32x4*)(s + i);
  f32x4 b = *(const f32x4*)(s + i + 4);
  bf16x8 o;
#pragma unroll
  for (int j = 0; j < 4; ++j) {
    o[j] = (__bf16)a[j];
    o[4 + j] = (__bf16)b[j];
  }
  *(bf16x8*)(d + i) = o;
}

// ---------------------------------------------------------------- GEMM (B^T)
// C[M,N] = A[M,K] * B[N,K]^T   (A,B bf16; C dtype CT)
// EPI=0: store. EPI=1: += R (residual). EPI=2: *= silu(R) (R=w1x, in-place h).
template <int EPI, typename CT, typename RT>
__global__ __launch_bounds__(256) void gemm_bt(
    const __bf16* __restrict__ A, const __bf16* __restrict__ B,
    CT* C, const RT* R, int M, int N, int K) {
  __shared__ __attribute__((aligned(16))) __bf16 sA[128 * 32];
  __shared__ __attribute__((aligned(16))) __bf16 sB[128 * 32];
  const int tid = threadIdx.x;
  const int lane = tid & 63;
  const int wave = tid >> 6;
  const int wm = (wave >> 1) << 6;   // wave's 64x64 quadrant
  const int wn = (wave & 1) << 6;
  const int ln15 = lane & 15;
  const int kq8 = (lane >> 4) << 3;  // quad*8
  const long blockM = (long)blockIdx.y << 7;
  const long blockN = (long)blockIdx.x << 7;

  // staging: thread t covers row t/4 (and +64), k-cols (t%4)*8..+8; LDS dest is
  // linear in lane (base + lane*16B) per the global_load_lds G5 caveat.
  const int srow = tid >> 2;
  const int scol = (tid & 3) << 3;
  const __bf16* gA = A + (blockM + srow) * (long)K + scol;
  const __bf16* gB = B + (blockN + srow) * (long)K + scol;
  __bf16* lA = sA + tid * 8;
  __bf16* lB = sB + tid * 8;

  f32x4 acc[4][4] = {};
  const int KT = K >> 5;

  async_cp16(gA, lA);
  async_cp16(gA + 64 * (long)K, lA + 2048);
  async_cp16(gB, lB);
  async_cp16(gB + 64 * (long)K, lB + 2048);

  for (int kt = 0; kt < KT; ++kt) {
    __builtin_amdgcn_s_waitcnt(0);  // drain this wave's global_load_lds
    __syncthreads();                // all waves' staging visible
    bf16x8 af[4], bfr[4];
#pragma unroll
    for (int i = 0; i < 4; ++i)
      af[i] = *(const bf16x8*)&sA[(wm + i * 16 + ln15) * 32 + kq8];
#pragma unroll
    for (int j = 0; j < 4; ++j)
      bfr[j] = *(const bf16x8*)&sB[(wn + j * 16 + ln15) * 32 + kq8];
    __syncthreads();                // frag reads done before re-staging
    if (kt + 1 < KT) {
      const __bf16* a2 = gA + (long)(kt + 1) * 32;
      const __bf16* b2 = gB + (long)(kt + 1) * 32;
      async_cp16(a2, lA);
      async_cp16(a2 + 64 * (long)K, lA + 2048);
      async_cp16(b2, lB);
      async_cp16(b2 + 64 * (long)K, lB + 2048);
    }
#pragma unroll
    for (int i = 0; i < 4; ++i)
#pragma unroll
      for (int j = 0; j < 4; ++j)
        acc[i][j] = MFMA16(af[i], bfr[j], acc[i][j]);
  }

  // C/D layout (m89): col = lane&15, row = quad*4 + reg
  const int rq4 = (lane >> 4) << 2;
#pragma unroll
  for (int i = 0; i < 4; ++i)
#pragma unroll
    for (int j = 0; j < 4; ++j)
#pragma unroll
      for (int r = 0; r < 4; ++r) {
        const long grow = blockM + wm + i * 16 + rq4 + r;
        const long gcol = blockN + wn + j * 16 + ln15;
        const long idx = grow * N + gcol;
        float v = acc[i][j][r];
        if (EPI == 1) v += (float)R[idx];
        if (EPI == 2) {
          const float w = (float)R[idx];
          v *= w / (1.f + __expf(-w));  // silu(w1x) * (xn2.W3^T)
        }
        C[idx] = (CT)v;
      }
}

// ------------------------------------------------------------ flash attention
// One wave per (b, h, q-tile PAIR). Pair (p, 127-p): nkt(p)+nkt(127-p) ~= 65
// for every p -> uniform work per wave. A's key range is a prefix of B's, so
// K-frags and V-frags are loaded once and feed both tiles' MFMAs.
__device__ __forceinline__ void sm_update(const f32x4 s[2], float mrow[4],
                                          float lrow[4], f32x4 oacc[8],
                                          __bf16* sP, int qb, int kbase,
                                          int ln15, int quad) {
  const float scale = 0.08838834764831845f;  // 1/sqrt(128)
  const float NEG = -1.0e4f;                 // finite; |true score| < ~1e2
#pragma unroll
  for (int r = 0; r < 4; ++r) {
    const int qrow = qb + quad * 4 + r;
    const bool m0 = (kbase + ln15 > qrow);
    const bool m1 = (kbase + 16 + ln15 > qrow);
    const float s0 = m0 ? NEG : s[0][r] * scale;
    const float s1 = m1 ? NEG : s[1][r] * scale;
    float tm = fmaxf(s0, s1);
#pragma unroll
    for (int off = 1; off < 16; off <<= 1) tm = fmaxf(tm, __shfl_xor(tm, off));
    const float mnew = fmaxf(mrow[r], tm);
    const float alpha = __expf(mrow[r] - mnew);  // arg <= 0: no inf
    mrow[r] = mnew;
    const float p0 = m0 ? 0.f : __expf(s0 - mnew);
    const float p1 = m1 ? 0.f : __expf(s1 - mnew);
    float rs = p0 + p1;
#pragma unroll
    for (int off = 1; off < 16; off <<= 1) rs += __shfl_xor(rs, off);
    lrow[r] = lrow[r] * alpha + rs;
#pragma unroll
    for (int nt = 0; nt < 8; ++nt) oacc[nt][r] *= alpha;
    sP[(quad * 4 + r) * 32 + ln15] = (__bf16)p0;
    sP[(quad * 4 + r) * 32 + 16 + ln15] = (__bf16)p1;
  }
}

__global__ __launch_bounds__(64, 2) void attn_k(
    const __bf16* __restrict__ q, const __bf16* __restrict__ k,
    const __bf16* __restrict__ v, __bf16* __restrict__ o) {
  __shared__ __attribute__((aligned(16))) __bf16 sPA[16 * 32];
  __shared__ __attribute__((aligned(16))) __bf16 sPB[16 * 32];
  const int lane = threadIdx.x;
  const int ln15 = lane & 15;
  const int quad = lane >> 4;
  // XCD-clustered mapping: dispatch round-robins lin%8 across XCDs; give each
  // XCD 4 exclusive (b,h) panels (4 x 1MB K+V = its 4MB L2).
  const int lin = blockIdx.x + 64 * (blockIdx.y + 16 * blockIdx.z);
  const int xcd = lin & 7;
  const int j = lin >> 3;                 // 0..255
  const int panel = xcd * 4 + (j >> 6);   // 0..31
  const int p = j & 63;                   // pair index 0..63
  const int b = panel >> 4;
  const int h = panel & 15;
  const int S = 2048;
  const int qbA = p << 4;                 // light tile
  const int qbB = (127 - p) << 4;         // heavy tile
  const long bh = (long)b * S * 2048 + h * 128;

  bf16x8 qfA[4], qfB[4];  // A-frag (m120): Q[m=ln15][d = kb*32 + quad*8 + j]
  {
    const __bf16* qpA = q + bh + (long)(qbA + ln15) * 2048 + quad * 8;
    const __bf16* qpB = q + bh + (long)(qbB + ln15) * 2048 + quad * 8;
#pragma unroll
    for (int kb = 0; kb < 4; ++kb) {
      qfA[kb] = *(const bf16x8*)(qpA + kb * 32);
      qfB[kb] = *(const bf16x8*)(qpB + kb * 32);
    }
  }

  const float NEG = -1.0e4f;
  f32x4 oaccA[8] = {}, oaccB[8] = {};
  float mrowA[4] = {NEG, NEG, NEG, NEG}, mrowB[4] = {NEG, NEG, NEG, NEG};
  float lrowA[4] = {}, lrowB[4] = {};

  const int nktA = ((p) + 2) >> 1;        // A active for kt in [0, nktA)
  const int nktB = ((127 - p) + 2) >> 1;  // loop bound (A range is a prefix)

  for (int kt = 0; kt < nktB; ++kt) {
    const int kbase = kt << 5;
    const bool doA = (kt < nktA);
    f32x4 sA[2] = {}, sB[2] = {};
    if (doA) {
#pragma unroll
      for (int c = 0; c < 2; ++c) {
        const __bf16* kp =
            k + bh + (long)(kbase + c * 16 + ln15) * 2048 + quad * 8;
#pragma unroll
        for (int kb = 0; kb < 4; ++kb) {
          bf16x8 kf = *(const bf16x8*)(kp + kb * 32);
          sB[c] = MFMA16(qfB[kb], kf, sB[c]);
          sA[c] = MFMA16(qfA[kb], kf, sA[c]);
        }
      }
    } else {
#pragma unroll
      for (int c = 0; c < 2; ++c) {
        const __bf16* kp =
            k + bh + (long)(kbase + c * 16 + ln15) * 2048 + quad * 8;
#pragma unroll
        for (int kb = 0; kb < 4; ++kb) {
          bf16x8 kf = *(const bf16x8*)(kp + kb * 32);
          sB[c] = MFMA16(qfB[kb], kf, sB[c]);
        }
      }
    }

    sm_update(sB, mrowB, lrowB, oaccB, sPB, qbB, kbase, ln15, quad);
    if (doA) sm_update(sA, mrowA, lrowA, oaccA, sPA, qbA, kbase, ln15, quad);

    __syncthreads();  // P writes -> visible for transposed read
    bf16x8 paB = *(const bf16x8*)&sPB[ln15 * 32 + quad * 8];
    bf16x8 paA = {};
    if (doA) paA = *(const bf16x8*)&sPA[ln15 * 32 + quad * 8];
    __syncthreads();  // reads retired before next iter's writes

    const __bf16* vbase = v + bh + (long)kbase * 2048;
    if (doA) {
#pragma unroll
      for (int nt = 0; nt < 8; ++nt) {
        bf16x8 vf;  // B-frag: V[key = quad*8 + j][dim = nt*16 + ln15]
        const __bf16* vp = vbase + (long)(quad * 8) * 2048 + nt * 16 + ln15;
#pragma unroll
        for (int jj = 0; jj < 8; ++jj) vf[jj] = vp[(long)jj * 2048];
        oaccB[nt] = MFMA16(paB, vf, oaccB[nt]);
        oaccA[nt] = MFMA16(paA, vf, oaccA[nt]);
      }
    } else {
#pragma unroll
      for (int nt = 0; nt < 8; ++nt) {
        bf16x8 vf;
        const __bf16* vp = vbase + (long)(quad * 8) * 2048 + nt * 16 + ln15;
#pragma unroll
        for (int jj = 0; jj < 8; ++jj) vf[jj] = vp[(long)jj * 2048];
        oaccB[nt] = MFMA16(paB, vf, oaccB[nt]);
      }
    }
  }

  __bf16* opB = o + bh + (long)qbB * 2048;
  __bf16* opA = o + bh + (long)qbA * 2048;
#pragma unroll
  for (int nt = 0; nt < 8; ++nt)
#pragma unroll
    for (int r = 0; r < 4; ++r) {
      opB[(long)(quad * 4 + r) * 2048 + nt * 16 + ln15] =
          (__bf16)(oaccB[nt][r] / lrowB[r]);
      opA[(long)(quad * 4 + r) * 2048 + nt * 16 + ln15] =
          (__bf16)(oaccA[nt][r] / lrowA[r]);
    }
}

// ------------------------------------------------------ RMSNorm (f32 -> bf16)
__global__ __launch_bounds__(256) void rmsnorm_k(
    const float* __restrict__ x, const float* __restrict__ g,
    __bf16* __restrict__ out) {
  __shared__ float red[4];
  const int row = blockIdx.x;
  const int tid = threadIdx.x;
  f32x4 xa = *(const f32x4*)(x + (long)row * 2048 + tid * 8);
  f32x4 xb = *(const f32x4*)(x + (long)row * 2048 + tid * 8 + 4);
  float xf[8];
  float ss = 0.f;
#pragma unroll
  for (int j = 0; j < 4; ++j) {
    xf[j] = xa[j];
    xf[4 + j] = xb[j];
  }
#pragma unroll
  for (int j = 0; j < 8; ++j) ss += xf[j] * xf[j];
#pragma unroll
  for (int off = 32; off > 0; off >>= 1) ss += __shfl_xor(ss, off);
  if ((tid & 63) == 0) red[tid >> 6] = ss;
  __syncthreads();
  const float inv = rsqrtf((red[0] + red[1] + red[2] + red[3]) * (1.f / 2048.f) + 1e-5f);
  f32x4 ga = *(const f32x4*)(g + tid * 8);
  f32x4 gb = *(const f32x4*)(g + tid * 8 + 4);
  bf16x8 ov;
#pragma unroll
  for (int j = 0; j < 4; ++j) {
    ov[j] = (__bf16)(xf[j] * inv * ga[j]);
    ov[4 + j] = (__bf16)(xf[4 + j] * inv * gb[j]);
  }
  *(bf16x8*)(out + (long)row * 2048 + tid * 8) = ov;
}

// ----------------------------------------------------------------- RoPE (bf16)
__global__ __launch_bounds__(256) void rope_k(__bf16* __restrict__ t) {
  const long idx = (long)blockIdx.x * 256 + threadIdx.x;  // (row, h, kpair)
  const int kp = idx & 63;
  const int h = (idx >> 6) & 15;
  const long row = idx >> 10;
  const int pos = (int)(row & 2047);
  const float freq = exp2f((float)kp * (-13.287712379549449f / 64.0f));
  float sn, cs;
  sincosf((float)pos * freq, &sn, &cs);
  __bf16* p = t + row * 2048 + h * 128 + kp * 2;
  const float e = (float)p[0], od = (float)p[1];
  p[0] = (__bf16)(e * cs - od * sn);
  p[1] = (__bf16)(e * sn + od * cs);
}

// -------------------------------------------------------------------- launcher
extern "C" void kernel_launch(void* const* d_in, const int* in_sizes, int n_in,
                              void* d_out, int out_size, void* d_ws, size_t ws_size,
                              hipStream_t stream) {
  const float* x = (const float*)d_in[0];
  const float* Wq = (const float*)d_in[1];
  const float* Wk = (const float*)d_in[2];
  const float* Wv = (const float*)d_in[3];
  const float* Wo = (const float*)d_in[4];
  const float* W1 = (const float*)d_in[5];
  const float* W2 = (const float*)d_in[6];
  const float* W3 = (const float*)d_in[7];
  const float* g1 = (const float*)d_in[8];
  const float* g2 = (const float*)d_in[9];
  float* out = (float*)d_out;
  char* ws = (char*)d_ws;

  const long NDD = 2048L * 2048;   // 4,194,304
  const long NFD = 5504L * 2048;   // 11,272,192
  const long WSLOT = 22544384;     // NFD * 2 bytes (max weight, bf16)
  const long MB16 = 16777216;      // 4096*2048*2 bytes (bf16 activation)

  __bf16* wslot = (__bf16*)(ws);                  // rotating bf16 weight
  __bf16* xn = (__bf16*)(ws + WSLOT);             // rmsnorm1 out / attn out
  __bf16* qb = (__bf16*)(ws + WSLOT + MB16);      // q
  __bf16* kb = (__bf16*)(ws + WSLOT + 2 * MB16);  // k
  __bf16* vb = (__bf16*)(ws + WSLOT + 3 * MB16);  // v
  __bf16* attn = xn;
  __bf16* xn2 = vb;        // v dead after attn; rmsnorm2 out lives here
  __bf16* w1x = xn;        // 43MB over dead xn+q+k span [WSLOT, WSLOT+45.1MB);
                           // ends 67.6MB < xn2 offset 72.9MB -- disjoint.
  // peak ws: WSLOT + 4*MB16 = 89.7MB

  rmsnorm_k<<<4096, 256, 0, stream>>>(x, g1, xn);

  cvt_k<<<2048, 256, 0, stream>>>(Wq, wslot, NDD);
  gemm_bt<0, __bf16, float><<<dim3(16, 32), 256, 0, stream>>>(
      xn, wslot, qb, nullptr, 4096, 2048, 2048);
  cvt_k<<<2048, 256, 0, stream>>>(Wk, wslot, NDD);
  gemm_bt<0, __bf16, float><<<dim3(16, 32), 256, 0, stream>>>(
      xn, wslot, kb, nullptr, 4096, 2048, 2048);
  cvt_k<<<2048, 256, 0, stream>>>(Wv, wslot, NDD);
  gemm_bt<0, __bf16, float><<<dim3(16, 32), 256, 0, stream>>>(
      xn, wslot, vb, nullptr, 4096, 2048, 2048);

  rope_k<<<16384, 256, 0, stream>>>(qb);
  rope_k<<<16384, 256, 0, stream>>>(kb);
  attn_k<<<dim3(64, 16, 2), 64, 0, stream>>>(qb, kb, vb, attn);

  cvt_k<<<2048, 256, 0, stream>>>(Wo, wslot, NDD);
  gemm_bt<1, float, float><<<dim3(16, 32), 256, 0, stream>>>(
      attn, wslot, out, x, 4096, 2048, 2048);  // out = attn.Wo^T + x (f32)

  rmsnorm_k<<<4096, 256, 0, stream>>>(out, g2, xn2);

  cvt_k<<<5504, 256, 0, stream>>>(W1, wslot, NFD);
  gemm_bt<0, __bf16, float><<<dim3(43, 32), 256, 0, stream>>>(
      xn2, wslot, w1x, nullptr, 4096, 5504, 2048);
  cvt_k<<<5504, 256, 0, stream>>>(W3, wslot, NFD);
  gemm_bt<2, __bf16, __bf16><<<dim3(43, 32), 256, 0, stream>>>(
      xn2, wslot, w1x, w1x, 4096, 5504, 2048);  // h = silu(w1x)*w3x in-place
  cvt_k<<<5504, 256, 0, stream>>>(W2, wslot, NFD);
  gemm_bt<1, float, float><<<dim3(16, 32), 256, 0, stream>>>(
      w1x, wslot, out, out, 4096, 2048, 5504);  // out += h.W2^T (f32)
}

// Round 4
// 1001.366 us; speedup vs baseline: 1.2794x; 1.0263x over previous
//
#include <hip/hip_runtime.h>
#include <hip/hip_bf16.h>
#include <math.h>

// Transformer block for MI355X (gfx950). Inputs/outputs are FLOAT32 (per the
// reference contract); compute is bf16-MFMA internally.
// GEMMs (R7 = R6's change, kept for bisect): m97 structure widened to BK=64
//   (half the barrier drains) with both-sides XOR swizzle (linear
//   global_load_lds dest + pre-swizzled global source col + swizzled ds_read
//   col) -> conflict-free b128 reads.
// Attention (R7): EXACT R5 kernel (known-good, 201us): balanced q-tile pairs
//   (p, 127-p) per wave, K/V frag sharing, XCD-clustered panels (K/V L2-res).
//   R6's split-K attn REVERTED pending bisect result.
// Weights converted f32->bf16 just-in-time into one rotating workspace slot.

typedef __bf16 bf16x8 __attribute__((ext_vector_type(8)));
typedef float f32x4 __attribute__((ext_vector_type(4)));

#define MFMA16(a, b, c) __builtin_amdgcn_mfma_f32_16x16x32_bf16(a, b, c, 0, 0, 0)

__device__ __forceinline__ void async_cp16(const void* g, void* l) {
  __builtin_amdgcn_global_load_lds((__attribute__((address_space(1))) void*)g,
                                   (__attribute__((address_space(3))) void*)l,
                                   16, 0, 0);
}

// --------------------------------------------------------------- f32 -> bf16
__global__ __launch_bounds__(256) void cvt_k(const float* __restrict__ s,
                                             __bf16* __restrict__ d, long n) {
  const long i = ((long)blockIdx.x * 256 + threadIdx.x) * 8;
  if (i >= n) return;
  f32x4 a = *(const f32x4*)(s + i);
  f32x4 b = *(const f32x4*)(s + i + 4);
  bf16x8 o;
#pragma unroll
  for (int j = 0; j < 4; ++j) {
    o[j] = (__bf16)a[j];
    o[4 + j] = (__bf16)b[j];
  }
  *(bf16x8*)(d + i) = o;
}

// ---------------------------------------------------------------- GEMM (B^T)
// C[M,N] = A[M,K] * B[N,K]^T   (A,B bf16; C dtype CT). BK=64.
// EPI=0: store. EPI=1: += R (residual). EPI=2: *= silu(R) (R=w1x, in-place h).
template <int EPI, typename CT, typename RT>
__global__ __launch_bounds__(256) void gemm_bt(
    const __bf16* __restrict__ A, const __bf16* __restrict__ B,
    CT* C, const RT* R, int M, int N, int K) {
  __shared__ __attribute__((aligned(16))) __bf16 sA[128 * 64];
  __shared__ __attribute__((aligned(16))) __bf16 sB[128 * 64];
  const int tid = threadIdx.x;
  const int lane = tid & 63;
  const int wave = tid >> 6;
  const int wm = (wave >> 1) << 6;   // wave's 64x64 quadrant
  const int wn = (wave & 1) << 6;
  const int ln15 = lane & 15;
  const int quad = lane >> 4;
  const long blockM = (long)blockIdx.y << 7;
  const long blockN = (long)blockIdx.x << 7;

  // Staging (rule 21, both-sides swizzle): thread t writes LDS bytes
  // [t*16,+16) + rr*4096 = logical (row = t/8 + rr*32, col-byte c' = (t&7)*16)
  // of the [128][64] bf16 tile. Reads access (row, c ^ ((row&7)<<4)), so the
  // GLOBAL source col is pre-swizzled: c = c' ^ ((srow&7)<<4). Constant per
  // thread (rr*32 == 0 mod 8). Trace: t=17 (row2,c'=16) <- gcol-byte 48; read
  // row2 wants bytes 48..63 -> addr 2*128 + (48^32) = 272..287 = t17's. OK
  const int srow = tid >> 3;                          // 0..31
  const int scolb = ((tid & 7) ^ (srow & 7)) << 4;    // swizzled src col byte
  const __bf16* gA = A + (blockM + srow) * (long)K + (scolb >> 1);
  const __bf16* gB = B + (blockN + srow) * (long)K + (scolb >> 1);
  __bf16* lA = sA + tid * 8;
  __bf16* lB = sB + tid * 8;

  f32x4 acc[4][4] = {};
  const int KT = K >> 6;

#pragma unroll
  for (int rr = 0; rr < 4; ++rr) {
    async_cp16(gA + (long)rr * 32 * K, lA + rr * 2048);
    async_cp16(gB + (long)rr * 32 * K, lB + rr * 2048);
  }

  const char* sAb = (const char*)sA;
  const char* sBb = (const char*)sB;
  const int rsw = (ln15 & 7) << 4;
  const int cbk[2] = {(quad << 4) ^ rsw, (64 | (quad << 4)) ^ rsw};

  for (int kt = 0; kt < KT; ++kt) {
    __builtin_amdgcn_s_waitcnt(0);  // drain this wave's global_load_lds
    __syncthreads();                // all waves' staging visible
    bf16x8 af[2][4], bfr[2][4];
#pragma unroll
    for (int i = 0; i < 4; ++i) {
      const int ra = (wm + i * 16 + ln15) << 7;  // row*128B (row&7 == ln15&7)
      const int rb = (wn + i * 16 + ln15) << 7;
#pragma unroll
      for (int kk = 0; kk < 2; ++kk) {
        af[kk][i] = *(const bf16x8*)(sAb + ra + cbk[kk]);
        bfr[kk][i] = *(const bf16x8*)(sBb + rb + cbk[kk]);
      }
    }
    __syncthreads();                // frag reads done before re-staging
    if (kt + 1 < KT) {
      const __bf16* a2 = gA + (long)(kt + 1) * 64;
      const __bf16* b2 = gB + (long)(kt + 1) * 64;
#pragma unroll
      for (int rr = 0; rr < 4; ++rr) {
        async_cp16(a2 + (long)rr * 32 * K, lA + rr * 2048);
        async_cp16(b2 + (long)rr * 32 * K, lB + rr * 2048);
      }
    }
#pragma unroll
    for (int kk = 0; kk < 2; ++kk)
#pragma unroll
      for (int i = 0; i < 4; ++i)
#pragma unroll
        for (int j = 0; j < 4; ++j)
          acc[i][j] = MFMA16(af[kk][i], bfr[kk][j], acc[i][j]);
  }

  // C/D layout (m89): col = lane&15, row = quad*4 + reg
  const int rq4 = (lane >> 4) << 2;
#pragma unroll
  for (int i = 0; i < 4; ++i)
#pragma unroll
    for (int j = 0; j < 4; ++j)
#pragma unroll
      for (int r = 0; r < 4; ++r) {
        const long grow = blockM + wm + i * 16 + rq4 + r;
        const long gcol = blockN + wn + j * 16 + ln15;
        const long idx = grow * N + gcol;
        float v = acc[i][j][r];
        if (EPI == 1) v += (float)R[idx];
        if (EPI == 2) {
          const float w = (float)R[idx];
          v *= w / (1.f + __expf(-w));  // silu(w1x) * (xn2.W3^T)
        }
        C[idx] = (CT)v;
      }
}

// ------------------------------------------------------------ flash attention
// One wave per (b, h, q-tile PAIR). Pair (p, 127-p): nkt(p)+nkt(127-p) ~= 65
// for every p -> uniform work per wave. A's key range is a prefix of B's, so
// K-frags and V-frags are loaded once and feed both tiles' MFMAs.
__device__ __forceinline__ void sm_update(const f32x4 s[2], float mrow[4],
                                          float lrow[4], f32x4 oacc[8],
                                          __bf16* sP, int qb, int kbase,
                                          int ln15, int quad) {
  const float scale = 0.08838834764831845f;  // 1/sqrt(128)
  const float NEG = -1.0e4f;                 // finite; |true score| < ~1e2
#pragma unroll
  for (int r = 0; r < 4; ++r) {
    const int qrow = qb + quad * 4 + r;
    const bool m0 = (kbase + ln15 > qrow);
    const bool m1 = (kbase + 16 + ln15 > qrow);
    const float s0 = m0 ? NEG : s[0][r] * scale;
    const float s1 = m1 ? NEG : s[1][r] * scale;
    float tm = fmaxf(s0, s1);
#pragma unroll
    for (int off = 1; off < 16; off <<= 1) tm = fmaxf(tm, __shfl_xor(tm, off));
    const float mnew = fmaxf(mrow[r], tm);
    const float alpha = __expf(mrow[r] - mnew);  // arg <= 0: no inf
    mrow[r] = mnew;
    const float p0 = m0 ? 0.f : __expf(s0 - mnew);
    const float p1 = m1 ? 0.f : __expf(s1 - mnew);
    float rs = p0 + p1;
#pragma unroll
    for (int off = 1; off < 16; off <<= 1) rs += __shfl_xor(rs, off);
    lrow[r] = lrow[r] * alpha + rs;
#pragma unroll
    for (int nt = 0; nt < 8; ++nt) oacc[nt][r] *= alpha;
    sP[(quad * 4 + r) * 32 + ln15] = (__bf16)p0;
    sP[(quad * 4 + r) * 32 + 16 + ln15] = (__bf16)p1;
  }
}

__global__ __launch_bounds__(64, 2) void attn_k(
    const __bf16* __restrict__ q, const __bf16* __restrict__ k,
    const __bf16* __restrict__ v, __bf16* __restrict__ o) {
  __shared__ __attribute__((aligned(16))) __bf16 sPA[16 * 32];
  __shared__ __attribute__((aligned(16))) __bf16 sPB[16 * 32];
  const int lane = threadIdx.x;
  const int ln15 = lane & 15;
  const int quad = lane >> 4;
  // XCD-clustered mapping: dispatch round-robins lin%8 across XCDs; give each
  // XCD 4 exclusive (b,h) panels (4 x 1MB K+V = its 4MB L2).
  const int lin = blockIdx.x + 64 * (blockIdx.y + 16 * blockIdx.z);
  const int xcd = lin & 7;
  const int j = lin >> 3;                 // 0..255
  const int panel = xcd * 4 + (j >> 6);   // 0..31
  const int p = j & 63;                   // pair index 0..63
  const int b = panel >> 4;
  const int h = panel & 15;
  const int S = 2048;
  const int qbA = p << 4;                 // light tile
  const int qbB = (127 - p) << 4;         // heavy tile
  const long bh = (long)b * S * 2048 + h * 128;

  bf16x8 qfA[4], qfB[4];  // A-frag (m120): Q[m=ln15][d = kb*32 + quad*8 + j]
  {
    const __bf16* qpA = q + bh + (long)(qbA + ln15) * 2048 + quad * 8;
    const __bf16* qpB = q + bh + (long)(qbB + ln15) * 2048 + quad * 8;
#pragma unroll
    for (int kb = 0; kb < 4; ++kb) {
      qfA[kb] = *(const bf16x8*)(qpA + kb * 32);
      qfB[kb] = *(const bf16x8*)(qpB + kb * 32);
    }
  }

  const float NEG = -1.0e4f;
  f32x4 oaccA[8] = {}, oaccB[8] = {};
  float mrowA[4] = {NEG, NEG, NEG, NEG}, mrowB[4] = {NEG, NEG, NEG, NEG};
  float lrowA[4] = {}, lrowB[4] = {};

  const int nktA = ((p) + 2) >> 1;        // A active for kt in [0, nktA)
  const int nktB = ((127 - p) + 2) >> 1;  // loop bound (A range is a prefix)

  for (int kt = 0; kt < nktB; ++kt) {
    const int kbase = kt << 5;
    const bool doA = (kt < nktA);
    f32x4 sA[2] = {}, sB[2] = {};
    if (doA) {
#pragma unroll
      for (int c = 0; c < 2; ++c) {
        const __bf16* kp =
            k + bh + (long)(kbase + c * 16 + ln15) * 2048 + quad * 8;
#pragma unroll
        for (int kb = 0; kb < 4; ++kb) {
          bf16x8 kf = *(const bf16x8*)(kp + kb * 32);
          sB[c] = MFMA16(qfB[kb], kf, sB[c]);
          sA[c] = MFMA16(qfA[kb], kf, sA[c]);
        }
      }
    } else {
#pragma unroll
      for (int c = 0; c < 2; ++c) {
        const __bf16* kp =
            k + bh + (long)(kbase + c * 16 + ln15) * 2048 + quad * 8;
#pragma unroll
        for (int kb = 0; kb < 4; ++kb) {
          bf16x8 kf = *(const bf16x8*)(kp + kb * 32);
          sB[c] = MFMA16(qfB[kb], kf, sB[c]);
        }
      }
    }

    sm_update(sB, mrowB, lrowB, oaccB, sPB, qbB, kbase, ln15, quad);
    if (doA) sm_update(sA, mrowA, lrowA, oaccA, sPA, qbA, kbase, ln15, quad);

    __syncthreads();  // P writes -> visible for transposed read
    bf16x8 paB = *(const bf16x8*)&sPB[ln15 * 32 + quad * 8];
    bf16x8 paA = {};
    if (doA) paA = *(const bf16x8*)&sPA[ln15 * 32 + quad * 8];
    __syncthreads();  // reads retired before next iter's writes

    const __bf16* vbase = v + bh + (long)kbase * 2048;
    if (doA) {
#pragma unroll
      for (int nt = 0; nt < 8; ++nt) {
        bf16x8 vf;  // B-frag: V[key = quad*8 + j][dim = nt*16 + ln15]
        const __bf16* vp = vbase + (long)(quad * 8) * 2048 + nt * 16 + ln15;
#pragma unroll
        for (int jj = 0; jj < 8; ++jj) vf[jj] = vp[(long)jj * 2048];
        oaccB[nt] = MFMA16(paB, vf, oaccB[nt]);
        oaccA[nt] = MFMA16(paA, vf, oaccA[nt]);
      }
    } else {
#pragma unroll
      for (int nt = 0; nt < 8; ++nt) {
        bf16x8 vf;
        const __bf16* vp = vbase + (long)(quad * 8) * 2048 + nt * 16 + ln15;
#pragma unroll
        for (int jj = 0; jj < 8; ++jj) vf[jj] = vp[(long)jj * 2048];
        oaccB[nt] = MFMA16(paB, vf, oaccB[nt]);
      }
    }
  }

  __bf16* opB = o + bh + (long)qbB * 2048;
  __bf16* opA = o + bh + (long)qbA * 2048;
#pragma unroll
  for (int nt = 0; nt < 8; ++nt)
#pragma unroll
    for (int r = 0; r < 4; ++r) {
      opB[(long)(quad * 4 + r) * 2048 + nt * 16 + ln15] =
          (__bf16)(oaccB[nt][r] / lrowB[r]);
      opA[(long)(quad * 4 + r) * 2048 + nt * 16 + ln15] =
          (__bf16)(oaccA[nt][r] / lrowA[r]);
    }
}

// ------------------------------------------------------ RMSNorm (f32 -> bf16)
__global__ __launch_bounds__(256) void rmsnorm_k(
    const float* __restrict__ x, const float* __restrict__ g,
    __bf16* __restrict__ out) {
  __shared__ float red[4];
  const int row = blockIdx.x;
  const int tid = threadIdx.x;
  f32x4 xa = *(const f32x4*)(x + (long)row * 2048 + tid * 8);
  f32x4 xb = *(const f32x4*)(x + (long)row * 2048 + tid * 8 + 4);
  float xf[8];
  float ss = 0.f;
#pragma unroll
  for (int j = 0; j < 4; ++j) {
    xf[j] = xa[j];
    xf[4 + j] = xb[j];
  }
#pragma unroll
  for (int j = 0; j < 8; ++j) ss += xf[j] * xf[j];
#pragma unroll
  for (int off = 32; off > 0; off >>= 1) ss += __shfl_xor(ss, off);
  if ((tid & 63) == 0) red[tid >> 6] = ss;
  __syncthreads();
  const float inv = rsqrtf((red[0] + red[1] + red[2] + red[3]) * (1.f / 2048.f) + 1e-5f);
  f32x4 ga = *(const f32x4*)(g + tid * 8);
  f32x4 gb = *(const f32x4*)(g + tid * 8 + 4);
  bf16x8 ov;
#pragma unroll
  for (int j = 0; j < 4; ++j) {
    ov[j] = (__bf16)(xf[j] * inv * ga[j]);
    ov[4 + j] = (__bf16)(xf[4 + j] * inv * gb[j]);
  }
  *(bf16x8*)(out + (long)row * 2048 + tid * 8) = ov;
}

// ----------------------------------------------------------------- RoPE (bf16)
__global__ __launch_bounds__(256) void rope_k(__bf16* __restrict__ t) {
  const long idx = (long)blockIdx.x * 256 + threadIdx.x;  // (row, h, kpair)
  const int kp = idx & 63;
  const int h = (idx >> 6) & 15;
  const long row = idx >> 10;
  const int pos = (int)(row & 2047);
  const float freq = exp2f((float)kp * (-13.287712379549449f / 64.0f));
  float sn, cs;
  sincosf((float)pos * freq, &sn, &cs);
  __bf16* p = t + row * 2048 + h * 128 + kp * 2;
  const float e = (float)p[0], od = (float)p[1];
  p[0] = (__bf16)(e * cs - od * sn);
  p[1] = (__bf16)(e * sn + od * cs);
}

// -------------------------------------------------------------------- launcher
extern "C" void kernel_launch(void* const* d_in, const int* in_sizes, int n_in,
                              void* d_out, int out_size, void* d_ws, size_t ws_size,
                              hipStream_t stream) {
  const float* x = (const float*)d_in[0];
  const float* Wq = (const float*)d_in[1];
  const float* Wk = (const float*)d_in[2];
  const float* Wv = (const float*)d_in[3];
  const float* Wo = (const float*)d_in[4];
  const float* W1 = (const float*)d_in[5];
  const float* W2 = (const float*)d_in[6];
  const float* W3 = (const float*)d_in[7];
  const float* g1 = (const float*)d_in[8];
  const float* g2 = (const float*)d_in[9];
  float* out = (float*)d_out;
  char* ws = (char*)d_ws;

  const long NDD = 2048L * 2048;   // 4,194,304
  const long NFD = 5504L * 2048;   // 11,272,192
  const long WSLOT = 22544384;     // NFD * 2 bytes (max weight, bf16)
  const long MB16 = 16777216;      // 4096*2048*2 bytes (bf16 activation)

  __bf16* wslot = (__bf16*)(ws);                  // rotating bf16 weight
  __bf16* xn = (__bf16*)(ws + WSLOT);             // rmsnorm1 out / attn out
  __bf16* qb = (__bf16*)(ws + WSLOT + MB16);      // q
  __bf16* kb = (__bf16*)(ws + WSLOT + 2 * MB16);  // k
  __bf16* vb = (__bf16*)(ws + WSLOT + 3 * MB16);  // v
  __bf16* attn = xn;
  __bf16* xn2 = vb;        // v dead after attn; rmsnorm2 out lives here
  __bf16* w1x = xn;        // 43MB over dead xn+q+k span [WSLOT, WSLOT+45.1MB);
                           // ends 67.6MB < xn2 offset 72.9MB -- disjoint.
  // peak ws: WSLOT + 4*MB16 = 89.7MB

  rmsnorm_k<<<4096, 256, 0, stream>>>(x, g1, xn);

  cvt_k<<<2048, 256, 0, stream>>>(Wq, wslot, NDD);
  gemm_bt<0, __bf16, float><<<dim3(16, 32), 256, 0, stream>>>(
      xn, wslot, qb, nullptr, 4096, 2048, 2048);
  cvt_k<<<2048, 256, 0, stream>>>(Wk, wslot, NDD);
  gemm_bt<0, __bf16, float><<<dim3(16, 32), 256, 0, stream>>>(
      xn, wslot, kb, nullptr, 4096, 2048, 2048);
  cvt_k<<<2048, 256, 0, stream>>>(Wv, wslot, NDD);
  gemm_bt<0, __bf16, float><<<dim3(16, 32), 256, 0, stream>>>(
      xn, wslot, vb, nullptr, 4096, 2048, 2048);

  rope_k<<<16384, 256, 0, stream>>>(qb);
  rope_k<<<16384, 256, 0, stream>>>(kb);
  attn_k<<<dim3(64, 16, 2), 64, 0, stream>>>(qb, kb, vb, attn);

  cvt_k<<<2048, 256, 0, stream>>>(Wo, wslot, NDD);
  gemm_bt<1, float, float><<<dim3(16, 32), 256, 0, stream>>>(
      attn, wslot, out, x, 4096, 2048, 2048);  // out = attn.Wo^T + x (f32)

  rmsnorm_k<<<4096, 256, 0, stream>>>(out, g2, xn2);

  cvt_k<<<5504, 256, 0, stream>>>(W1, wslot, NFD);
  gemm_bt<0, __bf16, float><<<dim3(43, 32), 256, 0, stream>>>(
      xn2, wslot, w1x, nullptr, 4096, 5504, 2048);
  cvt_k<<<5504, 256, 0, stream>>>(W3, wslot, NFD);
  gemm_bt<2, __bf16, __bf16><<<dim3(43, 32), 256, 0, stream>>>(
      xn2, wslot, w1x, w1x, 4096, 5504, 2048);  // h = silu(w1x)*w3x in-place
  cvt_k<<<5504, 256, 0, stream>>>(W2, wslot, NFD);
  gemm_bt<1, float, float><<<dim3(16, 32), 256, 0, stream>>>(
      w1x, wslot, out, out, 4096, 2048, 5504);  // out += h.W2^T (f32)
}

// Round 6
// 957.855 us; speedup vs baseline: 1.3375x; 1.0454x over previous
//
#include <hip/hip_runtime.h>
#include <hip/hip_bf16.h>
#include <math.h>

// Transformer block for MI355X (gfx950). Inputs/outputs are FLOAT32 (per the
// reference contract); compute is bf16-MFMA internally.
// GEMMs (R7, banked): m97 structure widened to BK=64 (half the barrier
//   drains) with both-sides XOR swizzle -> conflict-free b128 reads.
// Attention (R8, resubmitted R9 after infra failure): single-wave block =>
//   BOTH __syncthreads removed (per-wave DS ops are in-order; compiler
//   reorder blocked by asm memory fences).
//   Issue order per k-tile: 8 K b128 loads, then 64 V scalar loads, then QK
//   MFMAs (wait vmcnt(K-only)) -> V latency hides under QK+softmax+transpose
//   instead of being drained by the old barriers' s_waitcnt vmcnt(0).
//   Balanced q-tile pairs (p,127-p) + XCD-clustered panels (K/V L2-res) kept.
// Weights converted f32->bf16 just-in-time into one rotating workspace slot.

typedef __bf16 bf16x8 __attribute__((ext_vector_type(8)));
typedef float f32x4 __attribute__((ext_vector_type(4)));

#define MFMA16(a, b, c) __builtin_amdgcn_mfma_f32_16x16x32_bf16(a, b, c, 0, 0, 0)

__device__ __forceinline__ void async_cp16(const void* g, void* l) {
  __builtin_amdgcn_global_load_lds((__attribute__((address_space(1))) void*)g,
                                   (__attribute__((address_space(3))) void*)l,
                                   16, 0, 0);
}

// --------------------------------------------------------------- f32 -> bf16
__global__ __launch_bounds__(256) void cvt_k(const float* __restrict__ s,
                                             __bf16* __restrict__ d, long n) {
  const long i = ((long)blockIdx.x * 256 + threadIdx.x) * 8;
  if (i >= n) return;
  f32x4 a = *(const f32x4*)(s + i);
  f32x4 b = *(const f32x4*)(s + i + 4);
  bf16x8 o;
#pragma unroll
  for (int j = 0; j < 4; ++j) {
    o[j] = (__bf16)a[j];
    o[4 + j] = (__bf16)b[j];
  }
  *(bf16x8*)(d + i) = o;
}

// ---------------------------------------------------------------- GEMM (B^T)
// C[M,N] = A[M,K] * B[N,K]^T   (A,B bf16; C dtype CT). BK=64.
// EPI=0: store. EPI=1: += R (residual). EPI=2: *= silu(R) (R=w1x, in-place h).
template <int EPI, typename CT, typename RT>
__global__ __launch_bounds__(256) void gemm_bt(
    const __bf16* __restrict__ A, const __bf16* __restrict__ B,
    CT* C, const RT* R, int M, int N, int K) {
  __shared__ __attribute__((aligned(16))) __bf16 sA[128 * 64];
  __shared__ __attribute__((aligned(16))) __bf16 sB[128 * 64];
  const int tid = threadIdx.x;
  const int lane = tid & 63;
  const int wave = tid >> 6;
  const int wm = (wave >> 1) << 6;   // wave's 64x64 quadrant
  const int wn = (wave & 1) << 6;
  const int ln15 = lane & 15;
  const int quad = lane >> 4;
  const long blockM = (long)blockIdx.y << 7;
  const long blockN = (long)blockIdx.x << 7;

  // Staging (rule 21, both-sides swizzle): thread t writes LDS bytes
  // [t*16,+16) + rr*4096 = logical (row = t/8 + rr*32, col-byte c' = (t&7)*16)
  // of the [128][64] bf16 tile. Reads access (row, c ^ ((row&7)<<4)), so the
  // GLOBAL source col is pre-swizzled: c = c' ^ ((srow&7)<<4). Constant per
  // thread (rr*32 == 0 mod 8).
  const int srow = tid >> 3;                          // 0..31
  const int scolb = ((tid & 7) ^ (srow & 7)) << 4;    // swizzled src col byte
  const __bf16* gA = A + (blockM + srow) * (long)K + (scolb >> 1);
  const __bf16* gB = B + (blockN + srow) * (long)K + (scolb >> 1);
  __bf16* lA = sA + tid * 8;
  __bf16* lB = sB + tid * 8;

  f32x4 acc[4][4] = {};
  const int KT = K >> 6;

#pragma unroll
  for (int rr = 0; rr < 4; ++rr) {
    async_cp16(gA + (long)rr * 32 * K, lA + rr * 2048);
    async_cp16(gB + (long)rr * 32 * K, lB + rr * 2048);
  }

  const char* sAb = (const char*)sA;
  const char* sBb = (const char*)sB;
  const int rsw = (ln15 & 7) << 4;
  const int cbk[2] = {(quad << 4) ^ rsw, (64 | (quad << 4)) ^ rsw};

  for (int kt = 0; kt < KT; ++kt) {
    __builtin_amdgcn_s_waitcnt(0);  // drain this wave's global_load_lds
    __syncthreads();                // all waves' staging visible
    bf16x8 af[2][4], bfr[2][4];
#pragma unroll
    for (int i = 0; i < 4; ++i) {
      const int ra = (wm + i * 16 + ln15) << 7;  // row*128B (row&7 == ln15&7)
      const int rb = (wn + i * 16 + ln15) << 7;
#pragma unroll
      for (int kk = 0; kk < 2; ++kk) {
        af[kk][i] = *(const bf16x8*)(sAb + ra + cbk[kk]);
        bfr[kk][i] = *(const bf16x8*)(sBb + rb + cbk[kk]);
      }
    }
    __syncthreads();                // frag reads done before re-staging
    if (kt + 1 < KT) {
      const __bf16* a2 = gA + (long)(kt + 1) * 64;
      const __bf16* b2 = gB + (long)(kt + 1) * 64;
#pragma unroll
      for (int rr = 0; rr < 4; ++rr) {
        async_cp16(a2 + (long)rr * 32 * K, lA + rr * 2048);
        async_cp16(b2 + (long)rr * 32 * K, lB + rr * 2048);
      }
    }
#pragma unroll
    for (int kk = 0; kk < 2; ++kk)
#pragma unroll
      for (int i = 0; i < 4; ++i)
#pragma unroll
        for (int j = 0; j < 4; ++j)
          acc[i][j] = MFMA16(af[kk][i], bfr[kk][j], acc[i][j]);
  }

  // C/D layout (m89): col = lane&15, row = quad*4 + reg
  const int rq4 = (lane >> 4) << 2;
#pragma unroll
  for (int i = 0; i < 4; ++i)
#pragma unroll
    for (int j = 0; j < 4; ++j)
#pragma unroll
      for (int r = 0; r < 4; ++r) {
        const long grow = blockM + wm + i * 16 + rq4 + r;
        const long gcol = blockN + wn + j * 16 + ln15;
        const long idx = grow * N + gcol;
        float v = acc[i][j][r];
        if (EPI == 1) v += (float)R[idx];
        if (EPI == 2) {
          const float w = (float)R[idx];
          v *= w / (1.f + __expf(-w));  // silu(w1x) * (xn2.W3^T)
        }
        C[idx] = (CT)v;
      }
}

// ------------------------------------------------------------ flash attention
// One wave per (b, h, q-tile PAIR). Pair (p, 127-p): nkt(p)+nkt(127-p) ~= 65
// for every p -> uniform work per wave. A's key range is a prefix of B's, so
// K-frags and V-frags are loaded once and feed both tiles' MFMAs.
__device__ __forceinline__ void sm_update(const f32x4 s[2], float mrow[4],
                                          float lrow[4], f32x4 oacc[8],
                                          __bf16* sP, int qb, int kbase,
                                          int ln15, int quad) {
  const float scale = 0.08838834764831845f;  // 1/sqrt(128)
  const float NEG = -1.0e4f;                 // finite; |true score| < ~1e2
#pragma unroll
  for (int r = 0; r < 4; ++r) {
    const int qrow = qb + quad * 4 + r;
    const bool m0 = (kbase + ln15 > qrow);
    const bool m1 = (kbase + 16 + ln15 > qrow);
    const float s0 = m0 ? NEG : s[0][r] * scale;
    const float s1 = m1 ? NEG : s[1][r] * scale;
    float tm = fmaxf(s0, s1);
#pragma unroll
    for (int off = 1; off < 16; off <<= 1) tm = fmaxf(tm, __shfl_xor(tm, off));
    const float mnew = fmaxf(mrow[r], tm);
    const float alpha = __expf(mrow[r] - mnew);  // arg <= 0: no inf
    mrow[r] = mnew;
    const float p0 = m0 ? 0.f : __expf(s0 - mnew);
    const float p1 = m1 ? 0.f : __expf(s1 - mnew);
    float rs = p0 + p1;
#pragma unroll
    for (int off = 1; off < 16; off <<= 1) rs += __shfl_xor(rs, off);
    lrow[r] = lrow[r] * alpha + rs;
#pragma unroll
    for (int nt = 0; nt < 8; ++nt) oacc[nt][r] *= alpha;
    sP[(quad * 4 + r) * 32 + ln15] = (__bf16)p0;
    sP[(quad * 4 + r) * 32 + 16 + ln15] = (__bf16)p1;
  }
}

__global__ __launch_bounds__(64, 2) void attn_k(
    const __bf16* __restrict__ q, const __bf16* __restrict__ k,
    const __bf16* __restrict__ v, __bf16* __restrict__ o) {
  __shared__ __attribute__((aligned(16))) __bf16 sPA[16 * 32];
  __shared__ __attribute__((aligned(16))) __bf16 sPB[16 * 32];
  const int lane = threadIdx.x;
  const int ln15 = lane & 15;
  const int quad = lane >> 4;
  // XCD-clustered mapping: dispatch round-robins lin%8 across XCDs; give each
  // XCD 4 exclusive (b,h) panels (4 x 1MB K+V = its 4MB L2).
  const int lin = blockIdx.x + 64 * (blockIdx.y + 16 * blockIdx.z);
  const int xcd = lin & 7;
  const int j = lin >> 3;                 // 0..255
  const int panel = xcd * 4 + (j >> 6);   // 0..31
  const int p = j & 63;                   // pair index 0..63
  const int b = panel >> 4;
  const int h = panel & 15;
  const int S = 2048;
  const int qbA = p << 4;                 // light tile
  const int qbB = (127 - p) << 4;         // heavy tile
  const long bh = (long)b * S * 2048 + h * 128;

  bf16x8 qfA[4], qfB[4];  // A-frag (m120): Q[m=ln15][d = kb*32 + quad*8 + j]
  {
    const __bf16* qpA = q + bh + (long)(qbA + ln15) * 2048 + quad * 8;
    const __bf16* qpB = q + bh + (long)(qbB + ln15) * 2048 + quad * 8;
#pragma unroll
    for (int kb = 0; kb < 4; ++kb) {
      qfA[kb] = *(const bf16x8*)(qpA + kb * 32);
      qfB[kb] = *(const bf16x8*)(qpB + kb * 32);
    }
  }

  const float NEG = -1.0e4f;
  f32x4 oaccA[8] = {}, oaccB[8] = {};
  float mrowA[4] = {NEG, NEG, NEG, NEG}, mrowB[4] = {NEG, NEG, NEG, NEG};
  float lrowA[4] = {}, lrowB[4] = {};

  const int nktA = ((p) + 2) >> 1;        // A active for kt in [0, nktA)
  const int nktB = ((127 - p) + 2) >> 1;  // loop bound (A range is a prefix)

  for (int kt = 0; kt < nktB; ++kt) {
    const int kbase = kt << 5;
    const bool doA = (kt < nktA);

    // ---- issue K loads (8 x b128) FIRST, then V loads (64 scalar): the QK
    // MFMAs then wait only on the K subset (vmcnt keeps V in flight), and V's
    // latency hides under QK + softmax + P-transpose.
    bf16x8 kfr[2][4];
#pragma unroll
    for (int c = 0; c < 2; ++c) {
      const __bf16* kp =
          k + bh + (long)(kbase + c * 16 + ln15) * 2048 + quad * 8;
#pragma unroll
      for (int kb = 0; kb < 4; ++kb)
        kfr[c][kb] = *(const bf16x8*)(kp + kb * 32);
    }
    bf16x8 vfr[8];  // B-frag: V[key = quad*8 + jj][dim = nt*16 + ln15]
    {
      const __bf16* vp =
          v + bh + (long)(kbase + quad * 8) * 2048 + ln15;
#pragma unroll
      for (int nt = 0; nt < 8; ++nt)
#pragma unroll
        for (int jj = 0; jj < 8; ++jj)
          vfr[nt][jj] = vp[(long)jj * 2048 + nt * 16];
    }

    f32x4 sA[2] = {}, sB[2] = {};
    if (doA) {
#pragma unroll
      for (int c = 0; c < 2; ++c)
#pragma unroll
        for (int kb = 0; kb < 4; ++kb) {
          sB[c] = MFMA16(qfB[kb], kfr[c][kb], sB[c]);
          sA[c] = MFMA16(qfA[kb], kfr[c][kb], sA[c]);
        }
    } else {
#pragma unroll
      for (int c = 0; c < 2; ++c)
#pragma unroll
        for (int kb = 0; kb < 4; ++kb)
          sB[c] = MFMA16(qfB[kb], kfr[c][kb], sB[c]);
    }

    sm_update(sB, mrowB, lrowB, oaccB, sPB, qbB, kbase, ln15, quad);
    if (doA) sm_update(sA, mrowA, lrowA, oaccA, sPA, qbA, kbase, ln15, quad);

    // Single-wave block: per-wave DS ops are in-order, so no barrier needed
    // for the P write->transposed-read. The fence only blocks COMPILER
    // reordering (per-lane alias analysis could otherwise sink the writes).
    asm volatile("" ::: "memory");
    bf16x8 paB = *(const bf16x8*)&sPB[ln15 * 32 + quad * 8];
    bf16x8 paA = {};
    if (doA) paA = *(const bf16x8*)&sPA[ln15 * 32 + quad * 8];
    asm volatile("" ::: "memory");  // reads stay before next iter's writes

    if (doA) {
#pragma unroll
      for (int nt = 0; nt < 8; ++nt) {
        oaccB[nt] = MFMA16(paB, vfr[nt], oaccB[nt]);
        oaccA[nt] = MFMA16(paA, vfr[nt], oaccA[nt]);
      }
    } else {
#pragma unroll
      for (int nt = 0; nt < 8; ++nt)
        oaccB[nt] = MFMA16(paB, vfr[nt], oaccB[nt]);
    }
  }

  __bf16* opB = o + bh + (long)qbB * 2048;
  __bf16* opA = o + bh + (long)qbA * 2048;
#pragma unroll
  for (int nt = 0; nt < 8; ++nt)
#pragma unroll
    for (int r = 0; r < 4; ++r) {
      opB[(long)(quad * 4 + r) * 2048 + nt * 16 + ln15] =
          (__bf16)(oaccB[nt][r] / lrowB[r]);
      opA[(long)(quad * 4 + r) * 2048 + nt * 16 + ln15] =
          (__bf16)(oaccA[nt][r] / lrowA[r]);
    }
}

// ------------------------------------------------------ RMSNorm (f32 -> bf16)
__global__ __launch_bounds__(256) void rmsnorm_k(
    const float* __restrict__ x, const float* __restrict__ g,
    __bf16* __restrict__ out) {
  __shared__ float red[4];
  const int row = blockIdx.x;
  const int tid = threadIdx.x;
  f32x4 xa = *(const f32x4*)(x + (long)row * 2048 + tid * 8);
  f32x4 xb = *(const f32x4*)(x + (long)row * 2048 + tid * 8 + 4);
  float xf[8];
  float ss = 0.f;
#pragma unroll
  for (int j = 0; j < 4; ++j) {
    xf[j] = xa[j];
    xf[4 + j] = xb[j];
  }
#pragma unroll
  for (int j = 0; j < 8; ++j) ss += xf[j] * xf[j];
#pragma unroll
  for (int off = 32; off > 0; off >>= 1) ss += __shfl_xor(ss, off);
  if ((tid & 63) == 0) red[tid >> 6] = ss;
  __syncthreads();
  const float inv = rsqrtf((red[0] + red[1] + red[2] + red[3]) * (1.f / 2048.f) + 1e-5f);
  f32x4 ga = *(const f32x4*)(g + tid * 8);
  f32x4 gb = *(const f32x4*)(g + tid * 8 + 4);
  bf16x8 ov;
#pragma unroll
  for (int j = 0; j < 4; ++j) {
    ov[j] = (__bf16)(xf[j] * inv * ga[j]);
    ov[4 + j] = (__bf16)(xf[4 + j] * inv * gb[j]);
  }
  *(bf16x8*)(out + (long)row * 2048 + tid * 8) = ov;
}

// ----------------------------------------------------------------- RoPE (bf16)
__global__ __launch_bounds__(256) void rope_k(__bf16* __restrict__ t) {
  const long idx = (long)blockIdx.x * 256 + threadIdx.x;  // (row, h, kpair)
  const int kp = idx & 63;
  const int h = (idx >> 6) & 15;
  const long row = idx >> 10;
  const int pos = (int)(row & 2047);
  const float freq = exp2f((float)kp * (-13.287712379549449f / 64.0f));
  float sn, cs;
  sincosf((float)pos * freq, &sn, &cs);
  __bf16* p = t + row * 2048 + h * 128 + kp * 2;
  const float e = (float)p[0], od = (float)p[1];
  p[0] = (__bf16)(e * cs - od * sn);
  p[1] = (__bf16)(e * sn + od * cs);
}

// -------------------------------------------------------------------- launcher
extern "C" void kernel_launch(void* const* d_in, const int* in_sizes, int n_in,
                              void* d_out, int out_size, void* d_ws, size_t ws_size,
                              hipStream_t stream) {
  const float* x = (const float*)d_in[0];
  const float* Wq = (const float*)d_in[1];
  const float* Wk = (const float*)d_in[2];
  const float* Wv = (const float*)d_in[3];
  const float* Wo = (const float*)d_in[4];
  const float* W1 = (const float*)d_in[5];
  const float* W2 = (const float*)d_in[6];
  const float* W3 = (const float*)d_in[7];
  const float* g1 = (const float*)d_in[8];
  const float* g2 = (const float*)d_in[9];
  float* out = (float*)d_out;
  char* ws = (char*)d_ws;

  const long NDD = 2048L * 2048;   // 4,194,304
  const long NFD = 5504L * 2048;   // 11,272,192
  const long WSLOT = 22544384;     // NFD * 2 bytes (max weight, bf16)
  const long MB16 = 16777216;      // 4096*2048*2 bytes (bf16 activation)

  __bf16* wslot = (__bf16*)(ws);                  // rotating bf16 weight
  __bf16* xn = (__bf16*)(ws + WSLOT);             // rmsnorm1 out / attn out
  __bf16* qb = (__bf16*)(ws + WSLOT + MB16);      // q
  __bf16* kb = (__bf16*)(ws + WSLOT + 2 * MB16);  // k
  __bf16* vb = (__bf16*)(ws + WSLOT + 3 * MB16);  // v
  __bf16* attn = xn;
  __bf16* xn2 = vb;        // v dead after attn; rmsnorm2 out lives here
  __bf16* w1x = xn;        // 43MB over dead xn+q+k span [WSLOT, WSLOT+45.1MB);
                           // ends 67.6MB < xn2 offset 72.9MB -- disjoint.
  // peak ws: WSLOT + 4*MB16 = 89.7MB

  rmsnorm_k<<<4096, 256, 0, stream>>>(x, g1, xn);

  cvt_k<<<2048, 256, 0, stream>>>(Wq, wslot, NDD);
  gemm_bt<0, __bf16, float><<<dim3(16, 32), 256, 0, stream>>>(
      xn, wslot, qb, nullptr, 4096, 2048, 2048);
  cvt_k<<<2048, 256, 0, stream>>>(Wk, wslot, NDD);
  gemm_bt<0, __bf16, float><<<dim3(16, 32), 256, 0, stream>>>(
      xn, wslot, kb, nullptr, 4096, 2048, 2048);
  cvt_k<<<2048, 256, 0, stream>>>(Wv, wslot, NDD);
  gemm_bt<0, __bf16, float><<<dim3(16, 32), 256, 0, stream>>>(
      xn, wslot, vb, nullptr, 4096, 2048, 2048);

  rope_k<<<16384, 256, 0, stream>>>(qb);
  rope_k<<<16384, 256, 0, stream>>>(kb);
  attn_k<<<dim3(64, 16, 2), 64, 0, stream>>>(qb, kb, vb, attn);

  cvt_k<<<2048, 256, 0, stream>>>(Wo, wslot, NDD);
  gemm_bt<1, float, float><<<dim3(16, 32), 256, 0, stream>>>(
      attn, wslot, out, x, 4096, 2048, 2048);  // out = attn.Wo^T + x (f32)

  rmsnorm_k<<<4096, 256, 0, stream>>>(out, g2, xn2);

  cvt_k<<<5504, 256, 0, stream>>>(W1, wslot, NFD);
  gemm_bt<0, __bf16, float><<<dim3(43, 32), 256, 0, stream>>>(
      xn2, wslot, w1x, nullptr, 4096, 5504, 2048);
  cvt_k<<<5504, 256, 0, stream>>>(W3, wslot, NFD);
  gemm_bt<2, __bf16, __bf16><<<dim3(43, 32), 256, 0, stream>>>(
      xn2, wslot, w1x, w1x, 4096, 5504, 2048);  // h = silu(w1x)*w3x in-place
  cvt_k<<<5504, 256, 0, stream>>>(W2, wslot, NFD);
  gemm_bt<1, float, float><<<dim3(16, 32), 256, 0, stream>>>(
      w1x, wslot, out, out, 4096, 2048, 5504);  // out += h.W2^T (f32)
}